// Round 2
// baseline (908.615 us; speedup 1.0000x reference)
//
#include <hip/hip_runtime.h>
#include <hip/hip_bf16.h>
#include <hip/hip_fp16.h>
#include <stdint.h>

typedef float    f32x4 __attribute__((ext_vector_type(4)));
typedef float    fvec4 __attribute__((ext_vector_type(4)));
typedef _Float16 f16x8 __attribute__((ext_vector_type(8)));

#define D_MODEL 1024
#define D_FF    4096
#define NTOK    8192
#define CAP_ROWS 17408   // 68 * 256 (expert regions 256-aligned)
#define NROWBLK  68

// ---- workspace layout (bytes) ----
// WT buffer is shared: W1^T fp16 during GEMM1, then overwritten with W2^T for GEMM2.
#define OFF_WT  0UL            // 4*4096*1024*2 = 33,554,432
#define OFF_XG  33554432UL     // 17408*1024*2 = 35,651,584
#define OFF_H   69206016UL     // 17408*4096*2 = 142,606,336
#define OFF_CNT 211812352UL    // 4 int
#define OFF_CUR 211812368UL    // 4 int
#define OFF_OFS 211812384UL    // 5 int (+pad)
#define OFF_TOK 211812416UL    // 17408 int
#define OFF_WGT 211882048UL    // 17408 float
#define OFF_E12 211951680UL    // 8192 int
#define OFF_W12 211984448UL    // 16384 float
#define WS_NEED 212049984UL

__device__ __forceinline__ void gload_lds16(const void* g, void* l) {
  __builtin_amdgcn_global_load_lds(
      (const __attribute__((address_space(1))) unsigned int*)g,
      (__attribute__((address_space(3))) unsigned int*)l, 16, 0, 0);
}

// ---------------- router: fp32 logits, top-2, renormalized probs ----------------
__global__ __launch_bounds__(256) void router_k(
    const float* __restrict__ x, const float* __restrict__ Wr,
    const float* __restrict__ br, int* __restrict__ counts,
    int* __restrict__ e12, float* __restrict__ w12) {
  int wid = threadIdx.x >> 6, lane = threadIdx.x & 63;
  int t = blockIdx.x * 4 + wid;
  const float* xr = x + (size_t)t * D_MODEL;
  float a0 = 0.f, a1 = 0.f, a2 = 0.f, a3 = 0.f;
#pragma unroll
  for (int c = 0; c < 4; ++c) {
    int d0 = c * 256 + lane * 4;
    fvec4 xv = *(const fvec4*)(xr + d0);
#pragma unroll
    for (int j = 0; j < 4; ++j) {
      fvec4 wv = *(const fvec4*)(Wr + (size_t)(d0 + j) * 4);
      a0 += xv[j] * wv[0]; a1 += xv[j] * wv[1];
      a2 += xv[j] * wv[2]; a3 += xv[j] * wv[3];
    }
  }
#pragma unroll
  for (int m = 32; m; m >>= 1) {
    a0 += __shfl_xor(a0, m, 64); a1 += __shfl_xor(a1, m, 64);
    a2 += __shfl_xor(a2, m, 64); a3 += __shfl_xor(a3, m, 64);
  }
  if (lane == 0) {
    float l[4] = {a0 + br[0], a1 + br[1], a2 + br[2], a3 + br[3]};
    int e1 = 0; float m1 = l[0];
#pragma unroll
    for (int e = 1; e < 4; ++e) if (l[e] > m1) { m1 = l[e]; e1 = e; }
    int e2 = -1; float m2 = -1e30f;
#pragma unroll
    for (int e = 0; e < 4; ++e) if (e != e1 && l[e] > m2) { m2 = l[e]; e2 = e; }
    float tt = expf(m2 - m1);
    float w1 = 1.f / (1.f + tt), w2 = tt / (1.f + tt);
    atomicAdd(&counts[e1], 1); atomicAdd(&counts[e2], 1);
    e12[t] = e1 | (e2 << 8);
    w12[2 * t] = w1; w12[2 * t + 1] = w2;
  }
}

// ---------------- prefix: 256-aligned expert offsets ----------------
__global__ void prefix_k(const int* __restrict__ counts, int* __restrict__ offs,
                         int* __restrict__ cursor) {
  if (threadIdx.x == 0 && blockIdx.x == 0) {
    int o = 0;
#pragma unroll
    for (int e = 0; e < 4; ++e) {
      offs[e] = o; cursor[e] = o;
      o += (counts[e] + 255) & ~255;
    }
    offs[4] = o;
  }
}

// ---------------- scatter tokens into per-expert lists ----------------
__global__ __launch_bounds__(256) void lists_k(
    const int* __restrict__ e12, const float* __restrict__ w12,
    int* __restrict__ cursor, int* __restrict__ tok, float* __restrict__ wgt) {
  int t = blockIdx.x * 256 + threadIdx.x;
  int p = e12[t];
  int e1 = p & 255, e2 = p >> 8;
  int i1 = atomicAdd(&cursor[e1], 1); tok[i1] = t; wgt[i1] = w12[2 * t];
  int i2 = atomicAdd(&cursor[e2], 1); tok[i2] = t; wgt[i2] = w12[2 * t + 1];
}

// ---------------- gather x rows -> fp16, zero pad rows ----------------
__global__ __launch_bounds__(128) void gather_k(
    const float* __restrict__ x, const int* __restrict__ offs,
    const int* __restrict__ counts, const int* __restrict__ tok,
    _Float16* __restrict__ Xg) {
  int b = blockIdx.x;
  if (b >= offs[4]) return;
  int e = 0;
  while (e < 3 && b >= offs[e + 1]) ++e;
  int tid = threadIdx.x;
  f16x8 o;
  if (b < offs[e] + counts[e]) {
    int t = tok[b];
    const float* src = x + (size_t)t * D_MODEL + tid * 8;
    fvec4 v0 = *(const fvec4*)src;
    fvec4 v1 = *(const fvec4*)(src + 4);
#pragma unroll
    for (int j = 0; j < 4; ++j) { o[j] = (_Float16)v0[j]; o[4 + j] = (_Float16)v1[j]; }
  } else {
#pragma unroll
    for (int j = 0; j < 8; ++j) o[j] = (_Float16)0.f;
  }
  *(f16x8*)(Xg + (size_t)b * D_MODEL + tid * 8) = o;
}

// ---------------- transpose-convert weights: in[e][K][N] fp32 -> out[e][N][K] fp16 ----------------
__global__ __launch_bounds__(256) void wtrans_k(
    const float* __restrict__ in, _Float16* __restrict__ out, int K, int N) {
  __shared__ float tile[64][65];
  int e = blockIdx.z;
  int n0 = blockIdx.x * 64, k0 = blockIdx.y * 64;
  const float* src = in + (size_t)e * K * N;
  _Float16* dst = out + (size_t)e * K * N;
  int t = threadIdx.x;
  {
    int kk = t >> 2, nc = (t & 3) * 16;
    const float* p = src + (size_t)(k0 + kk) * N + n0 + nc;
#pragma unroll
    for (int j = 0; j < 4; ++j) {
      fvec4 v = *(const fvec4*)(p + j * 4);
      tile[kk][nc + j * 4 + 0] = v[0]; tile[kk][nc + j * 4 + 1] = v[1];
      tile[kk][nc + j * 4 + 2] = v[2]; tile[kk][nc + j * 4 + 3] = v[3];
    }
  }
  __syncthreads();
  {
    int nn = t >> 2, kb = (t & 3) * 16;
    f16x8 o0, o1;
#pragma unroll
    for (int j = 0; j < 8; ++j) o0[j] = (_Float16)tile[kb + j][nn];
#pragma unroll
    for (int j = 0; j < 8; ++j) o1[j] = (_Float16)tile[kb + 8 + j][nn];
    _Float16* q = dst + (size_t)(n0 + nn) * K + k0 + kb;
    *(f16x8*)q = o0;
    *((f16x8*)q + 1) = o1;
  }
}

// ---------------- 8-phase 256x256 MFMA GEMM ----------------
// A: [CAP_ROWS][KD] fp16 row-major; B: [4][NTOT][KD] fp16 (B^T layout).
// LDS (dynamic 128KB): A: buf*32KB + half*16KB ; B: +64KB same structure.
// Half-tile (HT) = 128 rows x 64 cols fp16 = 16KB, XOR-swizzled via pre-swizzled
// global source (linear gload_lds dest). Double-buffered by K-tile (BK=64).
// Waves: 8 = 2(M) x 4(N). Wave output rows: {h*128 + wr*64 .. +63} for h=0,1;
// cols: {q*128 + wc*32 .. +31} for q=0,1  -> phase (h,q) touches exactly HT
// A_h and B_q, enabling counted vmcnt(4) (never 0) across phase barriers.
// MODE 0: outH = f16(gelu(acc+bias)); MODE 1: atomicAdd(outF[tok][col], w*(acc+bias))
// with split-K: kz in 0..3, K-range kz*1024..+1024, bias only at kz==0. NT=16 both.

__device__ __forceinline__ f16x8 lds_frag(const char* base, int row, int kbyte) {
  return *(const f16x8*)(base + row * 128 + (kbyte ^ ((row & 7) << 4)));
}

template <int KD>
__device__ __forceinline__ void stage_ht(const _Float16* g0, int k0, char* lds, int tid) {
  int w = tid >> 6, l = tid & 63;
  int srow = l >> 3;
  int kx = (l & 7) ^ srow;                 // pre-swizzled global 16B chunk
  const _Float16* g = g0 + k0 + kx * 8;
#pragma unroll
  for (int j = 0; j < 2; ++j) {
    int c16 = j * 8 + w;                   // 16 chunks of 8 rows each
    gload_lds16(g + (size_t)(c16 * 8 + srow) * KD, lds + c16 * 1024);
  }
}

#define MFMA_QUAD(h, q, bf)                                                  \
  _Pragma("unroll") for (int m = 0; m < 4; ++m)                              \
  _Pragma("unroll") for (int n = 0; n < 2; ++n)                              \
  _Pragma("unroll") for (int kk = 0; kk < 2; ++kk)                           \
      acc[(h)*4 + m][(q)*2 + n] = __builtin_amdgcn_mfma_f32_16x16x32_f16(    \
          af[m*2 + kk], bf[n*2 + kk], acc[(h)*4 + m][(q)*2 + n], 0, 0, 0);

#define LGKM0 do { asm volatile("s_waitcnt lgkmcnt(0)" ::: "memory");        \
                   __builtin_amdgcn_sched_barrier(0); } while (0)
#define VM4   asm volatile("s_waitcnt vmcnt(4)" ::: "memory")
#define BAR   __builtin_amdgcn_s_barrier()

template <int KD, int MODE>
__global__ __launch_bounds__(512, 2) void gemm8_k(
    const _Float16* __restrict__ A, const _Float16* __restrict__ B,
    const float* __restrict__ bias, const int* __restrict__ offs,
    const int* __restrict__ counts, const int* __restrict__ tok,
    const float* __restrict__ wgt, _Float16* __restrict__ outH,
    float* __restrict__ outF, int NTOT) {
  extern __shared__ char smem[];
  // bijective XCD chunk swizzle over 1088 blocks (1088 % 8 == 0)
  int bid = blockIdx.x;
  int swz = (bid & 7) * 136 + (bid >> 3);
  int row = swz % NROWBLK;
  int cz  = swz / NROWBLK;
  int col, kz;
  if (MODE == 0) { col = cz; kz = 0; } else { col = cz & 3; kz = cz >> 2; }

  int rowBase = row * 256;
  if (rowBase >= offs[4]) return;
  int e = 0;
  while (e < 3 && rowBase >= offs[e + 1]) ++e;
  int eoff = offs[e], cnt = counts[e];
  if (rowBase >= eoff + cnt) return;  // pure-pad tile
  int colBase = col * 256;
  int kbase = kz * 1024;

  int tid = threadIdx.x;
  int lane = tid & 63, wid = tid >> 6;
  int wr = wid >> 2, wc = wid & 3;
  int ln = lane & 15, kq = (lane >> 4) * 16;

  const _Float16* Ag = A + (size_t)rowBase * KD;
  const _Float16* Bg = B + (size_t)e * NTOT * KD + (size_t)colBase * KD;
  const _Float16* Ag1 = Ag + (size_t)128 * KD;
  const _Float16* Bg1 = Bg + (size_t)128 * KD;

  f32x4 acc[8][4];
  f32x4 zero = {0.f, 0.f, 0.f, 0.f};
#pragma unroll
  for (int i = 0; i < 8; ++i)
#pragma unroll
    for (int jn = 0; jn < 4; ++jn) acc[i][jn] = zero;

  // prologue: stage tile 0 in issue order A0,B0,B1,A1; retire A0,B0
  stage_ht<KD>(Ag,  kbase, smem,                 tid);
  stage_ht<KD>(Bg,  kbase, smem + 65536,         tid);
  stage_ht<KD>(Bg1, kbase, smem + 65536 + 16384, tid);
  stage_ht<KD>(Ag1, kbase, smem + 16384,         tid);
  VM4;
  BAR;

  f16x8 af[8], bf0[4], bf1[4];
  const int NT = 16;

  for (int t = 0; t < NT; ++t) {
    const char* cA = smem + ((t & 1) << 15);
    const char* cB = smem + 65536 + ((t & 1) << 15);
    char* nA = smem + (((t + 1) & 1) << 15);
    char* nB = smem + 65536 + (((t + 1) & 1) << 15);
    int tn = (t + 1 < NT) ? t + 1 : NT - 1;   // dummy re-stage keeps vmcnt uniform
    int k0n = kbase + tn * 64;

    // ---- phase 1: quad(h=0,q=0); reads A0,B0; stages A0(next) ----
#pragma unroll
    for (int m = 0; m < 4; ++m)
#pragma unroll
      for (int kk = 0; kk < 2; ++kk)
        af[m*2 + kk] = lds_frag(cA, wr*64 + m*16 + ln, kk*64 + kq);
#pragma unroll
    for (int n = 0; n < 2; ++n)
#pragma unroll
      for (int kk = 0; kk < 2; ++kk)
        bf0[n*2 + kk] = lds_frag(cB, wc*32 + n*16 + ln, kk*64 + kq);
    stage_ht<KD>(Ag, k0n, nA, tid);
    BAR; LGKM0;
    __builtin_amdgcn_s_setprio(1);
    MFMA_QUAD(0, 0, bf0);
    __builtin_amdgcn_s_setprio(0);
    VM4;   // retire B1(t) -> readable in phase 2
    BAR;

    // ---- phase 2: quad(h=0,q=1); reads B1; stages B0(next) ----
#pragma unroll
    for (int n = 0; n < 2; ++n)
#pragma unroll
      for (int kk = 0; kk < 2; ++kk)
        bf1[n*2 + kk] = lds_frag(cB + 16384, wc*32 + n*16 + ln, kk*64 + kq);
    stage_ht<KD>(Bg, k0n, nB, tid);
    BAR; LGKM0;
    __builtin_amdgcn_s_setprio(1);
    MFMA_QUAD(0, 1, bf1);
    __builtin_amdgcn_s_setprio(0);
    VM4;   // retire A1(t) -> readable in phase 3
    BAR;

    // ---- phase 3: quad(h=1,q=0); reads A1; stages B1(next) ----
#pragma unroll
    for (int m = 0; m < 4; ++m)
#pragma unroll
      for (int kk = 0; kk < 2; ++kk)
        af[m*2 + kk] = lds_frag(cA + 16384, wr*64 + m*16 + ln, kk*64 + kq);
    stage_ht<KD>(Bg1, k0n, nB + 16384, tid);
    BAR; LGKM0;
    __builtin_amdgcn_s_setprio(1);
    MFMA_QUAD(1, 0, bf0);
    __builtin_amdgcn_s_setprio(0);
    BAR;   // no vm wait needed (phase 4 reads nothing new)

    // ---- phase 4: quad(h=1,q=1); no reads; stages A1(next) ----
    stage_ht<KD>(Ag1, k0n, nA + 16384, tid);
    BAR; LGKM0;
    __builtin_amdgcn_s_setprio(1);
    MFMA_QUAD(1, 1, bf1);
    __builtin_amdgcn_s_setprio(0);
    VM4;   // retire A0,B0(next) -> readable in next group's phase 1
    BAR;
  }

  // ---- epilogue ----  C/D frag: col = lane&15, row = (lane>>4)*4 + j
  float bv[4];
#pragma unroll
  for (int q = 0; q < 2; ++q)
#pragma unroll
    for (int n = 0; n < 2; ++n)
      bv[q*2 + n] = bias[(size_t)e * NTOT + colBase + q*128 + wc*32 + n*16 + ln];

  if (MODE == 0) {
#pragma unroll
    for (int h = 0; h < 2; ++h)
#pragma unroll
      for (int m = 0; m < 4; ++m) {
        int rbase = rowBase + h*128 + wr*64 + m*16 + (lane >> 4) * 4;
#pragma unroll
        for (int j = 0; j < 4; ++j) {
          size_t ro = (size_t)(rbase + j) * NTOT;
#pragma unroll
          for (int q = 0; q < 2; ++q)
#pragma unroll
            for (int n = 0; n < 2; ++n) {
              float v = acc[h*4 + m][q*2 + n][j] + bv[q*2 + n];
              v = 0.5f * v * (1.f + erff(v * 0.70710678118654752f));
              outH[ro + colBase + q*128 + wc*32 + n*16 + ln] = (_Float16)v;
            }
        }
      }
  } else {
    float bq[4];
#pragma unroll
    for (int i = 0; i < 4; ++i) bq[i] = (kz == 0) ? bv[i] : 0.f;
#pragma unroll
    for (int h = 0; h < 2; ++h)
#pragma unroll
      for (int m = 0; m < 4; ++m) {
        int rbase = rowBase + h*128 + wr*64 + m*16 + (lane >> 4) * 4;
#pragma unroll
        for (int j = 0; j < 4; ++j) {
          int grow = rbase + j;
          if (grow - eoff < cnt) {
            int tkn = tok[grow];
            float w = wgt[grow];
            size_t o = (size_t)tkn * D_MODEL + colBase;
#pragma unroll
            for (int q = 0; q < 2; ++q)
#pragma unroll
              for (int n = 0; n < 2; ++n)
                atomicAdd(&outF[o + q*128 + wc*32 + n*16 + ln],
                          w * (acc[h*4 + m][q*2 + n][j] + bq[q*2 + n]));
          }
        }
      }
  }
}

extern "C" void kernel_launch(void* const* d_in, const int* in_sizes, int n_in,
                              void* d_out, int out_size, void* d_ws, size_t ws_size,
                              hipStream_t stream) {
  const float* x  = (const float*)d_in[0];
  const float* Wr = (const float*)d_in[1];
  const float* br = (const float*)d_in[2];
  const float* W1 = (const float*)d_in[3];
  const float* b1 = (const float*)d_in[4];
  const float* W2 = (const float*)d_in[5];
  const float* b2 = (const float*)d_in[6];
  float* out = (float*)d_out;
  char* ws = (char*)d_ws;
  if (ws_size < WS_NEED) return;

  _Float16* WT = (_Float16*)(ws + OFF_WT);
  _Float16* Xg = (_Float16*)(ws + OFF_XG);
  _Float16* H  = (_Float16*)(ws + OFF_H);
  int*   counts = (int*)(ws + OFF_CNT);
  int*   cursor = (int*)(ws + OFF_CUR);
  int*   offs   = (int*)(ws + OFF_OFS);
  int*   tok    = (int*)(ws + OFF_TOK);
  float* wgt    = (float*)(ws + OFF_WGT);
  int*   e12    = (int*)(ws + OFF_E12);
  float* w12    = (float*)(ws + OFF_W12);

  hipFuncSetAttribute((const void*)gemm8_k<1024, 0>,
                      hipFuncAttributeMaxDynamicSharedMemorySize, 131072);
  hipFuncSetAttribute((const void*)gemm8_k<4096, 1>,
                      hipFuncAttributeMaxDynamicSharedMemorySize, 131072);

  hipMemsetAsync(counts, 0, 16, stream);
  hipMemsetAsync(d_out, 0, (size_t)out_size * sizeof(float), stream);

  router_k<<<NTOK / 4, 256, 0, stream>>>(x, Wr, br, counts, e12, w12);
  prefix_k<<<1, 64, 0, stream>>>(counts, offs, cursor);
  lists_k<<<NTOK / 256, 256, 0, stream>>>(e12, w12, cursor, tok, wgt);
  gather_k<<<CAP_ROWS, 128, 0, stream>>>(x, offs, counts, tok, Xg);

  // W1^T into WT, GEMM1, then W2^T into the SAME buffer, GEMM2 (stream-ordered).
  wtrans_k<<<dim3(64, 16, 4), 256, 0, stream>>>(W1, WT, 1024, 4096);
  gemm8_k<1024, 0><<<NROWBLK * 16, 512, 131072, stream>>>(
      Xg, WT, b1, offs, counts, tok, wgt, H, nullptr, D_FF);

  wtrans_k<<<dim3(16, 64, 4), 256, 0, stream>>>(W2, WT, 4096, 1024);
  gemm8_k<4096, 1><<<NROWBLK * 16, 512, 131072, stream>>>(
      H, WT, b2, offs, counts, tok, wgt, nullptr, out, D_MODEL);
}